// Round 7
// baseline (884.957 us; speedup 1.0000x reference)
//
#include <hip/hip_runtime.h>

typedef __attribute__((ext_vector_type(8))) _Float16 f16x8;
typedef __attribute__((ext_vector_type(4))) float f32x4;

namespace {
constexpr int N_PTS = 50000;
constexpr int VOUT  = 4;
constexpr int PPB   = 9;     // points per block
constexpr int ABYTES = 896;  // A row stride: 448 f16

// packed-weight region offsets in d_ws (f16 elements)
constexpr int OFF_BW1 = 0;        // V * (Kg=4)  * 256 * 8   (K 7 padded to 32)
constexpr int OFF_BW2 = 32768;    // V * (Kg=32) * 256 * 8
constexpr int OFF_AW1 = 294912;   // V * (Kg=56) * 256 * 8   (K=448)
constexpr int OFF_AW2 = 753664;   // V * (Kg=32) * 128 * 8
constexpr int PACK_TOTAL = 884736;
}

// ---- prep: fp32 weights -> f16, packed so lane's 8 k-elems are contiguous:
// Bp[g][n][j] with k = g*8+j, flat = (g*N + n)*8 + j  (zero-pad k >= Ksrc)
__global__ __launch_bounds__(256) void pack_weights_kernel(
    const float* __restrict__ bW1, const float* __restrict__ bW2,
    const float* __restrict__ aW1, const float* __restrict__ aW2,
    _Float16* __restrict__ out) {
  int t = blockIdx.x * 256 + threadIdx.x;
  const float* W; int Kg, N, Ksrc, base;
  if (t < OFF_BW2)      { base = OFF_BW1; Kg = 4;  N = 256; Ksrc = 7;   W = bW1; }
  else if (t < OFF_AW1) { base = OFF_BW2; Kg = 32; N = 256; Ksrc = 256; W = bW2; }
  else if (t < OFF_AW2) { base = OFF_AW1; Kg = 56; N = 256; Ksrc = 448; W = aW1; }
  else                  { base = OFF_AW2; Kg = 32; N = 128; Ksrc = 256; W = aW2; }
  int local = t - base;
  int vsz = Kg * N * 8;
  int v = local / vsz;
  int rem = local - v * vsz;
  int g  = rem / (N * 8);
  int r2 = rem - g * (N * 8);
  int n = r2 >> 3;
  int j = r2 & 7;
  int k = g * 8 + j;
  float val = (k < Ksrc) ? W[(v * Ksrc + k) * N + n] : 0.0f;
  out[t] = (_Float16)val;
}

// A-frag: lane l, elem j <-> A[16*mt + (l&15)][kb*32 + (l>>4)*8 + j]
// B-frag: lane l, elem j <-> B[kb*32 + (l>>4)*8 + j][n0 + 16*nt + (l&15)]
// C/D:    lane l, reg  r <-> C[16*mt + (l>>4)*4 + r][n0 + 16*nt + (l&15)]
template<int NT>
__device__ __forceinline__ void run_gemm(
    const _Float16* __restrict__ Bp, int Nn, int KB,
    const char* __restrict__ Ab, int abytes, int aswz,
    int lane, int n0, f32x4 acc[4][NT]) {
  const int q = lane >> 4, c = lane & 15;
  const char* Bb = (const char*)Bp;
  f16x8 bcur[NT], bnext[NT];
#pragma unroll
  for (int nt = 0; nt < NT; nt++)
    bcur[nt] = *(const f16x8*)(Bb + ((q * Nn + n0 + 16 * nt + c) << 4));
  for (int kb = 0; kb < KB; kb++) {
    f16x8 a[4];
    const int koff = (kb * 64 + q * 16) ^ aswz;
#pragma unroll
    for (int mt = 0; mt < 4; mt++)
      a[mt] = *(const f16x8*)(Ab + (16 * mt + c) * abytes + koff);
    if (kb + 1 < KB) {
#pragma unroll
      for (int nt = 0; nt < NT; nt++)
        bnext[nt] = *(const f16x8*)(Bb + ((((kb + 1) * 4 + q) * Nn + n0 + 16 * nt + c) << 4));
    }
#pragma unroll
    for (int mt = 0; mt < 4; mt++)
#pragma unroll
      for (int nt = 0; nt < NT; nt++)
        acc[mt][nt] = __builtin_amdgcn_mfma_f32_16x16x32_f16(a[mt], bcur[nt], acc[mt][nt], 0, 0, 0);
    if (kb + 1 < KB) {
#pragma unroll
      for (int nt = 0; nt < NT; nt++) bcur[nt] = bnext[nt];
    }
  }
}

template<int NT>
__device__ __forceinline__ void epilogue_relu(
    f32x4 acc[4][NT], const float* __restrict__ bias,
    int lane, int n0, char* __restrict__ Ab) {
  const int q = lane >> 4, c = lane & 15;
#pragma unroll
  for (int nt = 0; nt < NT; nt++) {
    const int col = n0 + 16 * nt + c;
    const float bv = bias[col];
#pragma unroll
    for (int mt = 0; mt < 4; mt++) {
#pragma unroll
      for (int r = 0; r < 4; r++) {
        const int row = 16 * mt + 4 * q + r;
        float y = fmaxf(acc[mt][nt][r] + bv, 0.0f);
        *(_Float16*)(Ab + row * ABYTES + ((2 * col) ^ (((4 * q + r) & 7) << 4))) = (_Float16)y;
      }
    }
  }
}

// 512 threads = 8 waves; each wave owns a 32-col slice (NT=2) of N=256.
// 16 waves/CU (2 blocks) = 4 waves/SIMD for MFMA/VALU cross-wave overlap.
__global__ __launch_bounds__(512, 4) void surf_mfma_kernel(
    const float* __restrict__ centers, const float* __restrict__ enc_g,
    const float* __restrict__ enc_node, const float* __restrict__ nbrs,
    const float* __restrict__ normals, const float* __restrict__ nbr_normals,
    const float* __restrict__ areas, const float* __restrict__ nbr_areas,
    const float* __restrict__ gpv, const float* __restrict__ gpr,
    const float* __restrict__ pW, const float* __restrict__ pb,
    const float* __restrict__ bb1, const float* __restrict__ bb2,
    const float* __restrict__ ab1, const float* __restrict__ ab2,
    const float* __restrict__ aW3, const float* __restrict__ ab3,
    const _Float16* __restrict__ Wp, float* __restrict__ out) {
  __shared__ _Float16 sA[64 * 448];    // [row][448] f16, XOR-swizzled 16B units
  __shared__ _Float16 sVol[64 * 40];   // [row][40] f16 (cols 7..31 zero, pad)
  __shared__ float sVolF[63][7];
  __shared__ alignas(16) float sPE[32];
  __shared__ float sPart[8][64];
  __shared__ float sRow[64];
  __shared__ float sInvd[54];

  const int t    = threadIdx.x;
  const int lane = t & 63;
  const int w    = t >> 6;             // 0..7
  const int blk  = blockIdx.x;
  char* Ab = (char*)sA;

  // ---- prologue phase 1: param_enc + vol rows ----
  if (t < 32) {
    float q0 = gpv[0] / gpr[0], q1 = gpv[1] / gpr[1];
    sPE[t] = fmaxf(fmaf(q0, pW[t], fmaf(q1, pW[32 + t], pb[t])), 0.0f);
  }
  if (t < 64) {
    float f[7];
    if (t < 63) {
      int pt = t / 7, p = t - pt * 7;
      int n = min(blk * PPB + pt, N_PTS - 1);
      if (p == 0) {
        f[0] = centers[n * 3];     f[1] = centers[n * 3 + 1]; f[2] = centers[n * 3 + 2];
        f[3] = normals[n * 3];     f[4] = normals[n * 3 + 1]; f[5] = normals[n * 3 + 2];
        f[6] = logf(areas[n]) * 0.1f;
      } else {
        int k = p - 1;
        int b3i = (n * 6 + k) * 3;
        f[0] = nbrs[b3i] + 1e-6f;        f[1] = nbrs[b3i + 1] + 1e-6f;
        f[2] = nbrs[b3i + 2] + 1e-6f;    f[3] = nbr_normals[b3i] + 1e-6f;
        f[4] = nbr_normals[b3i + 1] + 1e-6f; f[5] = nbr_normals[b3i + 2] + 1e-6f;
        f[6] = logf(nbr_areas[n * 6 + k]) * 0.1f + 1e-6f;
      }
#pragma unroll
      for (int j = 0; j < 7; j++) sVolF[t][j] = f[j];
    } else {
#pragma unroll
      for (int j = 0; j < 7; j++) f[j] = 0.0f;
    }
#pragma unroll
    for (int j = 0; j < 7; j++) sVol[t * 40 + j] = (_Float16)f[j];
#pragma unroll
    for (int j = 7; j < 40; j++) sVol[t * 40 + j] = (_Float16)0.0f;
  }
  __syncthreads();

  // ---- prologue phase 2: inv_dist + ctx (A cols 256..448), vectorized ----
  if (t < 54) {
    int pt = t / 6, k = t - pt * 6;
    float ss = 0.0f;
#pragma unroll
    for (int j = 0; j < 7; j++) {
      float d = sVolF[pt * 7][j] - sVolF[pt * 7 + 1 + k][j];
      ss = fmaf(d, d, ss);
    }
    sInvd[t] = 1.0f / sqrtf(ss);
  }
  // 63 rows x 24 groups of 8 cols; one f16x8 LDS store per group
  for (int task = t; task < 63 * 24; task += 512) {
    int row = task / 24, g = task - row * 24;
    int n = min(blk * PPB + row / 7, N_PTS - 1);
    float4 lo, hi;
    if (g < 4) {
      lo = *(const float4*)(enc_node + n * 32 + g * 8);
      hi = *(const float4*)(enc_node + n * 32 + g * 8 + 4);
    } else if (g < 20) {
      lo = *(const float4*)(enc_g + n * 128 + (g - 4) * 8);
      hi = *(const float4*)(enc_g + n * 128 + (g - 4) * 8 + 4);
    } else {
      lo = *(const float4*)(sPE + (g - 20) * 8);
      hi = *(const float4*)(sPE + (g - 20) * 8 + 4);
    }
    f16x8 pk;
    pk[0] = (_Float16)lo.x; pk[1] = (_Float16)lo.y; pk[2] = (_Float16)lo.z; pk[3] = (_Float16)lo.w;
    pk[4] = (_Float16)hi.x; pk[5] = (_Float16)hi.y; pk[6] = (_Float16)hi.z; pk[7] = (_Float16)hi.w;
    *(f16x8*)(Ab + row * ABYTES + ((512 + 16 * g) ^ ((row & 7) << 4))) = pk;
  }
  __syncthreads();

  const int aswz = (lane & 7) << 4;
  const int n0w  = 32 * w;

  for (int v = 0; v < VOUT; v++) {
    // ---- L1: vol(7 pad 32) @ bW1 -> sA[:, 0:256] ----
    {
      f32x4 acc[4][2] = {};
      run_gemm<2>(Wp + OFF_BW1 + v * 8192, 256, 1, (const char*)sVol, 80, 0, lane, n0w, acc);
      // reads sVol only; all readers of sA[0:256] finished >=2 barriers ago
      epilogue_relu<2>(acc, bb1 + v * 256, lane, n0w, Ab);
    }
    __syncthreads();
    // ---- L2: sA[0:256] @ bW2 -> sA[0:256] (in place) ----
    {
      f32x4 acc[4][2] = {};
      run_gemm<2>(Wp + OFF_BW2 + v * 65536, 256, 8, Ab, ABYTES, aswz, lane, n0w, acc);
      __syncthreads();
      epilogue_relu<2>(acc, bb2 + v * 256, lane, n0w, Ab);
    }
    __syncthreads();
    // ---- agg1: sA[0:448] @ aW1 -> sA[0:256] ----
    {
      f32x4 acc[4][2] = {};
      run_gemm<2>(Wp + OFF_AW1 + v * 114688, 256, 14, Ab, ABYTES, aswz, lane, n0w, acc);
      __syncthreads();
      epilogue_relu<2>(acc, ab1 + v * 256, lane, n0w, Ab);
    }
    __syncthreads();
    // ---- agg2 (256->128) fused with agg3 (128->1): all in registers ----
    {
      f32x4 acc[4][1] = {};
      run_gemm<1>(Wp + OFF_AW2 + v * 32768, 128, 8, Ab, ABYTES, aswz, lane, 16 * w, acc);
      const int col = 16 * w + (lane & 15);
      const float b2 = ab2[v * 128 + col];
      const float w3 = aW3[v * 128 + col];
      float part[16];
#pragma unroll
      for (int mt = 0; mt < 4; mt++)
#pragma unroll
        for (int r = 0; r < 4; r++)
          part[mt * 4 + r] = fmaxf(acc[mt][0][r] + b2, 0.0f) * w3;
#pragma unroll
      for (int i = 0; i < 16; i++) {
        float s = part[i];
        s += __shfl_xor(s, 1, 64);
        s += __shfl_xor(s, 2, 64);
        s += __shfl_xor(s, 4, 64);
        s += __shfl_xor(s, 8, 64);
        part[i] = s;
      }
      if ((lane & 15) == 0) {
        const int q = lane >> 4;
#pragma unroll
        for (int mt = 0; mt < 4; mt++)
#pragma unroll
          for (int r = 0; r < 4; r++)
            sPart[w][16 * mt + 4 * q + r] = part[mt * 4 + r];
      }
    }
    __syncthreads();
    // ---- final: 8-wave sum + inv-dist combine (wave 0 only, intra-wave) ----
    if (t < 64) {
      float s = ab3[v];
#pragma unroll
      for (int ww = 0; ww < 8; ww++) s += sPart[ww][t];
      sRow[t] = s;
    }
    if (t < PPB) {
      int n = blk * PPB + t;
      if (n < N_PTS) {
        float o0 = sRow[t * 7];
        float on = 0.0f, ds = 0.0f;
#pragma unroll
        for (int k = 0; k < 6; k++) {
          float id = sInvd[t * 6 + k];
          on = fmaf(sRow[t * 7 + 1 + k], id, on);
          ds += id;
        }
        out[n * VOUT + v] = 0.5f * o0 + 0.5f * on / ds;
      }
    }
    __syncthreads();
  }
}

extern "C" void kernel_launch(void* const* d_in, const int* in_sizes, int n_in,
                              void* d_out, int out_size, void* d_ws, size_t ws_size,
                              hipStream_t stream) {
  const float* centers     = (const float*)d_in[0];
  const float* enc_g       = (const float*)d_in[1];
  const float* enc_node    = (const float*)d_in[2];
  const float* nbrs        = (const float*)d_in[3];
  const float* normals     = (const float*)d_in[4];
  const float* nbr_normals = (const float*)d_in[5];
  const float* areas       = (const float*)d_in[6];
  const float* nbr_areas   = (const float*)d_in[7];
  const float* gpv         = (const float*)d_in[8];
  const float* gpr         = (const float*)d_in[9];
  const float* pW          = (const float*)d_in[10];
  const float* pb          = (const float*)d_in[11];
  const float* bW1         = (const float*)d_in[12];
  const float* bb1         = (const float*)d_in[13];
  const float* bW2         = (const float*)d_in[14];
  const float* bb2         = (const float*)d_in[15];
  const float* aW1         = (const float*)d_in[16];
  const float* ab1         = (const float*)d_in[17];
  const float* aW2         = (const float*)d_in[18];
  const float* ab2         = (const float*)d_in[19];
  const float* aW3         = (const float*)d_in[20];
  const float* ab3         = (const float*)d_in[21];
  float* out = (float*)d_out;
  _Float16* Wp = (_Float16*)d_ws;   // 1.77 MB packed f16 weights

  pack_weights_kernel<<<dim3(PACK_TOTAL / 256), dim3(256), 0, stream>>>(
      bW1, bW2, aW1, aW2, Wp);

  const int nblocks = (N_PTS + PPB - 1) / PPB;  // 5556
  surf_mfma_kernel<<<dim3(nblocks), dim3(512), 0, stream>>>(
      centers, enc_g, enc_node, nbrs, normals, nbr_normals, areas, nbr_areas,
      gpv, gpr, pW, pb, bb1, bb2, ab1, ab2, aW3, ab3, Wp, out);
}